// Round 6
// baseline (218.984 us; speedup 1.0000x reference)
//
#include <hip/hip_runtime.h>

// Problem constants (match reference)
#define Bq 8
#define Cq 128
#define Hq 128
#define Wq 256
#define Nq 1024
#define BN (Bq * Nq)
#define HWq (Hq * Wq)

#define LOG_2PI 1.8378770664093453f
#define EPSq 1e-9f

// 16-row windows, stride 12: stencil [y0-1, y0+2] of every y0 in
// [12*wi+1, 12*wi+12] (wi=0 also takes y0=0) fits rows [12*wi, 12*wi+16).
// Staging redundancy 16/12 = 1.33x (vs 2x in round 4).
#define RWIN 16
#define SWIN 12
#define NWIN 11              // wi = 0..10 covers y0 = 0..126
#define NBINSW (Bq * NWIN)   // 88
#define CAPW 1024            // worst case: all of a batch's samples in one bin
#define CCH 4                // channels per chunk
#define NCHUNK (Cq / CCH)    // 32
#define LROW 257             // padded px-row length (floats): banks ~2-way both sides

// ws layout (4-byte units)
#define BS_OFF 128
#define GEOM_OFF (BS_OFF + NBINSW * CAPW)          // 90240 (even: float2 ok)
#define PH_OFF  (GEOM_OFF + BN * 2)                // 106624
#define P2_OFF  (PH_OFF + NCHUNK * BN * 5)         // 1417344

// ---------------------------------------------------------------------------
__global__ void zero_bins(int* __restrict__ bc) {
    if (threadIdx.x < NBINSW) bc[threadIdx.x] = 0;
}

// ---------------------------------------------------------------------------
// Bin samples by (batch, window); precompute xs into geom (read once, not
// once per chunk-block). Atomic order only permutes bin lists; every
// sample's outputs are written to its own slot -> deterministic results.
// ---------------------------------------------------------------------------
__global__ __launch_bounds__(256) void binprep(
    const float* __restrict__ ub, const float* __restrict__ noise,
    int* __restrict__ bc, int* __restrict__ bs, float* __restrict__ geom)
{
    const int n = blockIdx.x * 256 + threadIdx.x;   // 0..BN-1
    const float2 u  = ((const float2*)ub)[n];
    const float2 nz = ((const float2*)noise)[n];
    const float xsx = u.x + nz.x;
    const float xsy = u.y + nz.y;
    ((float2*)geom)[n] = make_float2(xsx, xsy);

    float y = fminf(fmaxf(xsy, 0.0f), (float)(Hq - 1));
    int y0 = (int)floorf(y); y0 = min(max(y0, 0), Hq - 2);
    const int wi = (y0 == 0) ? 0 : (y0 - 1) / SWIN;      // 0..10
    const int bin = (n >> 10) * NWIN + wi;
    const int idx = atomicAdd(&bc[bin], 1);
    bs[bin * CAPW + idx] = n;                            // idx < 1024 always
}

// ---------------------------------------------------------------------------
// Binned Gauss-Newton partials. Block = (window-bin wb, channel-chunk).
// Stage 16 rows x 256 px x 4 ch (64 KB payload, 65.8 KB LDS) -- each
// (b,c,row) read is 1 KB contiguous float4. Then 128 groups of 4 lanes
// (lane = channel) process the bin's ~98 samples from LDS.
// ---------------------------------------------------------------------------
__global__ __launch_bounds__(512) void gn_binned(
    const float* __restrict__ fb,
    const float* __restrict__ f_t,
    const int* __restrict__ bc,
    const int* __restrict__ bs,
    const float* __restrict__ geom,
    float* __restrict__ pH)
{
    __shared__ float tile[RWIN * CCH * LROW];   // [(slot*4+c)][px] pad-257
    const int wb    = blockIdx.x >> 5;          // 0..87  (= b*NWIN + wi)
    const int chunk = blockIdx.x & 31;          // 0..31
    const int b  = wb / NWIN;
    const int wi = wb % NWIN;
    const int r0 = wi * SWIN;
    const int t  = threadIdx.x;

    // ---- stage: 64 (slot,c) rows, 8 threads each, 8 float4 per thread ----
    {
        const int cr = t >> 3;                  // 0..63
        const int slot = cr >> 2;               // 0..15
        const int c    = cr & 3;                // channel within chunk
        const int fq   = t & 7;
        const int row  = min(r0 + slot, Hq - 1);
        const float* src = fb + (((size_t)b * Cq + chunk * CCH + c) * Hq + row) * Wq;
        float* drow = tile + (size_t)(slot * CCH + c) * LROW;
        #pragma unroll
        for (int k = 0; k < 8; ++k) {
            const int f4 = fq + 8 * k;          // 0..63
            const float4 v = *(const float4*)(src + 4 * f4);
            drow[4 * f4 + 0] = v.x;
            drow[4 * f4 + 1] = v.y;
            drow[4 * f4 + 2] = v.z;
            drow[4 * f4 + 3] = v.w;
        }
    }
    __syncthreads();

    // ---- gather: 128 groups of 4 lanes; group -> sample, lane -> channel --
    const int nb = bc[wb];
    const int group = t >> 2;
    const int lc = t & 3;
    const int ch = chunk * CCH + lc;

    for (int s = group; s < nb; s += 128) {
        const int n = bs[wb * CAPW + s];
        const float2 xs = ((const float2*)geom)[n];
        const float xsx = xs.x, xsy = xs.y;

        float x = fminf(fmaxf(xsx, 0.0f), (float)(Wq - 1));
        float y = fminf(fmaxf(xsy, 0.0f), (float)(Hq - 1));
        int x0 = (int)floorf(x); x0 = min(max(x0, 0), Wq - 2);
        int y0 = (int)floorf(y); y0 = min(max(y0, 0), Hq - 2);
        const int x1 = x0 + 1, y1 = y0 + 1;
        const float wx = x - (float)x0;
        const float wy = y - (float)y0;

        const int xlo0 = max(x0 - 1, 0);
        const int xhi1 = min(x1 + 1, Wq - 1);
        const int ylo0 = max(y0 - 1, 0);
        const int yhi1 = min(y1 + 1, Hq - 1);
        const float sx0 = 1.0f / (float)(x1 - xlo0);
        const float sx1 = 1.0f / (float)(xhi1 - x0);
        const float sy0 = 1.0f / (float)(y1 - ylo0);
        const float sy1 = 1.0f / (float)(yhi1 - y0);

        // LDS slots (binning guarantees 0 <= ilo <= ihi <= 14)
        const int ilo = ylo0 - r0;
        const int i0  = y0   - r0;
        const int i1  = i0 + 1;
        const int ihi = yhi1 - r0;

        #define LD(ii, xx) tile[(size_t)((ii) * CCH + lc) * LROW + (xx)]
        const float f_lo0 = LD(ilo, x0), f_lo1 = LD(ilo, x1);
        const float f0m = LD(i0, xlo0), f00 = LD(i0, x0);
        const float f01 = LD(i0, x1),   f0p = LD(i0, xhi1);
        const float f1m = LD(i1, xlo0), f10 = LD(i1, x0);
        const float f11 = LD(i1, x1),   f1p = LD(i1, xhi1);
        const float f_hi0 = LD(ihi, x0), f_hi1 = LD(ihi, x1);
        #undef LD

        const float gx00 = (f01 - f0m) * sx0;
        const float gx01 = (f0p - f00) * sx1;
        const float gx10 = (f11 - f1m) * sx0;
        const float gx11 = (f1p - f10) * sx1;
        const float gy00 = (f10 - f_lo0) * sy0;
        const float gy01 = (f11 - f_lo1) * sy0;
        const float gy10 = (f_hi0 - f00) * sy1;
        const float gy11 = (f_hi1 - f01) * sy1;

        const float w00 = (1.0f - wx) * (1.0f - wy);
        const float w01 = wx * (1.0f - wy);
        const float w10 = (1.0f - wx) * wy;
        const float w11 = wx * wy;

        const float fs = f00 * w00 + f01 * w01 + f10 * w10 + f11 * w11;
        const float Jx = gx00 * w00 + gx01 * w01 + gx10 * w10 + gx11 * w11;
        const float Jy = gy00 * w00 + gy01 * w01 + gy10 * w10 + gy11 * w11;
        const float r  = fs - f_t[(size_t)n * Cq + ch];

        float hxx = Jx * Jx;
        float hxy = Jx * Jy;
        float hyy = Jy * Jy;
        float bx  = Jx * r;
        float by  = Jy * r;

        // reduce over the 4-lane group
        #pragma unroll
        for (int off = 1; off < 4; off <<= 1) {
            hxx += __shfl_xor(hxx, off);
            hxy += __shfl_xor(hxy, off);
            hyy += __shfl_xor(hyy, off);
            bx  += __shfl_xor(bx, off);
            by  += __shfl_xor(by, off);
        }
        if (lc == 0) {
            float* o = pH + ((size_t)chunk * BN + n) * 5;
            o[0] = hxx; o[1] = hxy; o[2] = hyy; o[3] = bx; o[4] = by;
        }
    }
}

// ---------------------------------------------------------------------------
// Per-sample finalize: sum the 32 chunk partials in fixed order, 2x2 GN
// solve, emit e1 contribution and log(det).
// ---------------------------------------------------------------------------
__global__ __launch_bounds__(256) void gn_finalA(
    const float* __restrict__ pH,
    const float* __restrict__ ub, const float* __restrict__ geom,
    float* __restrict__ p2)
{
    const int n = blockIdx.x * 256 + threadIdx.x;   // 0..BN-1
    float hxx = 0.0f, hxy = 0.0f, hyy = 0.0f, bx = 0.0f, by = 0.0f;
    #pragma unroll
    for (int k = 0; k < NCHUNK; ++k) {
        const float* o = pH + ((size_t)k * BN + n) * 5;
        hxx += o[0]; hxy += o[1]; hyy += o[2]; bx += o[3]; by += o[4];
    }

    const float2 u  = ((const float2*)ub)[n];
    const float2 xs = ((const float2*)geom)[n];

    const float A  = hxx + EPSq;
    const float Bv = hxy;
    const float D  = hyy + EPSq;

    const float det = A * D - Bv * Bv;
    const float inv = 1.0f / det;
    const float hbx = ( D * bx - Bv * by) * inv;
    const float hby = (-Bv * bx + A * by) * inv;
    const float dx = u.x - (xs.x - hbx);
    const float dy = u.y - (xs.y - hby);
    const float quad = A * dx * dx + 2.0f * Bv * dx * dy + D * dy * dy;

    const float detc = fmaxf(det, 1e-16f);
    p2[n]      = 0.5f * quad;
    p2[BN + n] = logf(detc);
}

// ---------------------------------------------------------------------------
// Single-block final reduction -> (e, e1, e2)
// ---------------------------------------------------------------------------
__global__ __launch_bounds__(1024) void gn_reduce_kernel(
    const float* __restrict__ p2, float* __restrict__ out)
{
    float s1 = 0.0f, s2 = 0.0f;
    for (int i = threadIdx.x; i < BN; i += 1024) {
        s1 += p2[i];
        s2 += p2[BN + i];
    }
    #pragma unroll
    for (int off = 32; off > 0; off >>= 1) {
        s1 += __shfl_down(s1, off);
        s2 += __shfl_down(s2, off);
    }
    __shared__ float l1[16], l2[16];
    const int w = threadIdx.x >> 6;
    if ((threadIdx.x & 63) == 0) { l1[w] = s1; l2[w] = s2; }
    __syncthreads();
    if (threadIdx.x == 0) {
        float e1 = 0.0f, sl = 0.0f;
        #pragma unroll
        for (int i = 0; i < 16; ++i) { e1 += l1[i]; sl += l2[i]; }
        const float e2 = (float)BN * LOG_2PI - 0.5f * sl;
        out[0] = e1 + (2.0f / 7.0f) * e2;  // e
        out[1] = e1;
        out[2] = e2;
    }
}

extern "C" void kernel_launch(void* const* d_in, const int* in_sizes, int n_in,
                              void* d_out, int out_size, void* d_ws, size_t ws_size,
                              hipStream_t stream) {
    const float* fb    = (const float*)d_in[0];
    const float* f_t   = (const float*)d_in[1];
    const float* ub    = (const float*)d_in[2];
    const float* noise = (const float*)d_in[3];
    float* out = (float*)d_out;
    int*   wsi = (int*)d_ws;
    float* wsf = (float*)d_ws;

    int*   bc   = wsi;                // 88 ints
    int*   bs   = wsi + BS_OFF;       // 88 * 1024 ints
    float* geom = wsf + GEOM_OFF;     // [BN] float2
    float* pH   = wsf + PH_OFF;       // [32][8192][5]
    float* p2   = wsf + P2_OFF;       // [2][8192]

    zero_bins<<<1, 128, 0, stream>>>(bc);
    binprep<<<BN / 256, 256, 0, stream>>>(ub, noise, bc, bs, geom);
    gn_binned<<<NBINSW * NCHUNK, 512, 0, stream>>>(fb, f_t, bc, bs, geom, pH);
    gn_finalA<<<BN / 256, 256, 0, stream>>>(pH, ub, geom, p2);
    gn_reduce_kernel<<<1, 1024, 0, stream>>>(p2, out);
}

// Round 7
// 213.738 us; speedup vs baseline: 1.0245x; 1.0245x over previous
//
#include <hip/hip_runtime.h>

// Problem constants (match reference)
#define Bq 8
#define Cq 128
#define Hq 128
#define Wq 256
#define Nq 1024
#define BN (Bq * Nq)
#define HWq (Hq * Wq)

#define LOG_2PI 1.8378770664093453f
#define EPSq 1e-9f

// R4 binning: rows [4g, 4g+8) per bin, y0 in [4g+1, 4g+4] (g=0 also y0=0)
#define NGRP 32
#define NBINS (Bq * NGRP)    // 256
#define BIN_CAP 1024
#define CCH 8                // channels per chunk
#define NCHUNK (Cq / CCH)    // 16

// ws layout (4-byte units)
#define BS_OFF 256
#define GEOM_OFF (BS_OFF + NBINS * BIN_CAP)        // 262400 (even -> float2 ok)
#define PH_OFF  (GEOM_OFF + BN * 2)                // 278784
#define P2_OFF  (PH_OFF + NCHUNK * BN * 5)         // 934144

// Direct global->LDS DMA, 16B per lane. LDS dest is wave-uniform base +
// lane*16 (linear); swizzle is applied on the GLOBAL source side (m173).
__device__ __forceinline__ void glds16(const float* g, float* l) {
    __builtin_amdgcn_global_load_lds(
        (const __attribute__((address_space(1))) void*)g,
        (__attribute__((address_space(3))) void*)l, 16, 0, 0);
}

// ---------------------------------------------------------------------------
__global__ void zero_bins(int* __restrict__ bc) { bc[threadIdx.x] = 0; }

// ---------------------------------------------------------------------------
// Bin samples by (batch, row-group); precompute xs into geom.
// Atomic order only permutes bin lists; all final values deterministic.
// ---------------------------------------------------------------------------
__global__ __launch_bounds__(256) void binprep(
    const float* __restrict__ ub, const float* __restrict__ noise,
    int* __restrict__ bc, int* __restrict__ bs, float* __restrict__ geom)
{
    const int n = blockIdx.x * 256 + threadIdx.x;   // 0..BN-1
    const float2 u  = ((const float2*)ub)[n];
    const float2 nz = ((const float2*)noise)[n];
    const float xsx = u.x + nz.x;
    const float xsy = u.y + nz.y;
    ((float2*)geom)[n] = make_float2(xsx, xsy);

    float y = fminf(fmaxf(xsy, 0.0f), (float)(Hq - 1));
    int y0 = (int)floorf(y); y0 = min(max(y0, 0), Hq - 2);
    const int g = (y0 == 0) ? 0 : ((y0 - 1) >> 2);  // 0..31
    const int bin = (n >> 10) * NGRP + g;
    const int idx = atomicAdd(&bc[bin], 1);
    bs[bin * BIN_CAP + idx] = n;                    // idx < 1024 always
}

// ---------------------------------------------------------------------------
// Binned GN partials. Block = (bin, chunk): 8 rows x 256 px x 8 ch.
// Staging: global_load_lds width=16. LDS layout [row=(slot*8+c)][256 px],
// linear (64 KB), with 16B-chunk XOR swizzle px4^=(row&7) applied on the
// global source; gather reads apply the same XOR -> group's 8 lanes
// (8 rows, same px) hit 8 distinct banks.
// ---------------------------------------------------------------------------
__global__ __launch_bounds__(512) void gn_binned(
    const float* __restrict__ fb,
    const float* __restrict__ f_t,
    const int* __restrict__ bc,
    const int* __restrict__ bs,
    const float* __restrict__ geom,
    float* __restrict__ pH)
{
    __shared__ float tile[64 * 256];             // 64 KB, linear
    const int bin   = blockIdx.x >> 4;           // 0..255
    const int chunk = blockIdx.x & 15;           // 0..15
    const int b = bin >> 5;
    const int g = bin & 31;
    const int t = threadIdx.x;

    // ---- stage: wave w fills rows w*8..w*8+7 (row = slot*8+c; slot=w, c=k)
    {
        const int w = t >> 6;                    // wave id (uniform)
        const int L = t & 63;                    // lane
        const int slot = w;
        const int row = min(4 * g + slot, Hq - 1);
        #pragma unroll
        for (int k = 0; k < 8; ++k) {
            const int c = k;                     // channel within chunk
            const float* src = fb
                + (((size_t)b * Cq + chunk * CCH + c) * Hq + row) * Wq
                + ((L ^ c) << 2);                // pre-swizzled 16B chunk
            glds16(src, &tile[(w * 8 + k) * 256]);
        }
    }
    __syncthreads();                             // drains vmcnt

    // ---- gather: 64 groups of 8 lanes; group -> sample, lane -> channel --
    const int nb = bc[bin];
    const int group = t >> 3;
    const int lc = t & 7;
    const int ch = chunk * CCH + lc;

    for (int s = group; s < nb; s += 64) {
        const int n = bs[bin * BIN_CAP + s];
        const float2 xs = ((const float2*)geom)[n];
        const float xsx = xs.x, xsy = xs.y;

        float x = fminf(fmaxf(xsx, 0.0f), (float)(Wq - 1));
        float y = fminf(fmaxf(xsy, 0.0f), (float)(Hq - 1));
        int x0 = (int)floorf(x); x0 = min(max(x0, 0), Wq - 2);
        int y0 = (int)floorf(y); y0 = min(max(y0, 0), Hq - 2);
        const int x1 = x0 + 1, y1 = y0 + 1;
        const float wx = x - (float)x0;
        const float wy = y - (float)y0;

        const int xlo0 = max(x0 - 1, 0);
        const int xhi1 = min(x1 + 1, Wq - 1);
        const int ylo0 = max(y0 - 1, 0);
        const int yhi1 = min(y1 + 1, Hq - 1);
        const float sx0 = 1.0f / (float)(x1 - xlo0);
        const float sx1 = 1.0f / (float)(xhi1 - x0);
        const float sy0 = 1.0f / (float)(y1 - ylo0);
        const float sy1 = 1.0f / (float)(yhi1 - y0);

        // LDS row slots (binning guarantees in [0,8))
        const int ilo = ylo0 - 4 * g;
        const int i0  = y0   - 4 * g;
        const int i1  = i0 + 1;
        const int ihi = yhi1 - 4 * g;

        // swizzled read: word = row*256 + ((px4 ^ lc)<<2) + (px&3), row&7==lc
        #define LD(ii, xx) tile[((ii) * 8 + lc) * 256 + (((((xx) >> 2) ^ lc) << 2) | ((xx) & 3))]
        const float f_lo0 = LD(ilo, x0), f_lo1 = LD(ilo, x1);
        const float f0m = LD(i0, xlo0), f00 = LD(i0, x0);
        const float f01 = LD(i0, x1),   f0p = LD(i0, xhi1);
        const float f1m = LD(i1, xlo0), f10 = LD(i1, x0);
        const float f11 = LD(i1, x1),   f1p = LD(i1, xhi1);
        const float f_hi0 = LD(ihi, x0), f_hi1 = LD(ihi, x1);
        #undef LD

        const float gx00 = (f01 - f0m) * sx0;
        const float gx01 = (f0p - f00) * sx1;
        const float gx10 = (f11 - f1m) * sx0;
        const float gx11 = (f1p - f10) * sx1;
        const float gy00 = (f10 - f_lo0) * sy0;
        const float gy01 = (f11 - f_lo1) * sy0;
        const float gy10 = (f_hi0 - f00) * sy1;
        const float gy11 = (f_hi1 - f01) * sy1;

        const float w00 = (1.0f - wx) * (1.0f - wy);
        const float w01 = wx * (1.0f - wy);
        const float w10 = (1.0f - wx) * wy;
        const float w11 = wx * wy;

        const float fs = f00 * w00 + f01 * w01 + f10 * w10 + f11 * w11;
        const float Jx = gx00 * w00 + gx01 * w01 + gx10 * w10 + gx11 * w11;
        const float Jy = gy00 * w00 + gy01 * w01 + gy10 * w10 + gy11 * w11;
        const float r  = fs - f_t[(size_t)n * Cq + ch];

        float hxx = Jx * Jx;
        float hxy = Jx * Jy;
        float hyy = Jy * Jy;
        float bx  = Jx * r;
        float by  = Jy * r;

        #pragma unroll
        for (int off = 1; off < 8; off <<= 1) {
            hxx += __shfl_xor(hxx, off);
            hxy += __shfl_xor(hxy, off);
            hyy += __shfl_xor(hyy, off);
            bx  += __shfl_xor(bx, off);
            by  += __shfl_xor(by, off);
        }
        if (lc == 0) {
            float* o = pH + ((size_t)chunk * BN + n) * 5;
            o[0] = hxx; o[1] = hxy; o[2] = hyy; o[3] = bx; o[4] = by;
        }
    }
}

// ---------------------------------------------------------------------------
// Per-sample finalize: sum 16 chunk partials (fixed order), 2x2 GN solve.
// ---------------------------------------------------------------------------
__global__ __launch_bounds__(256) void gn_finalA(
    const float* __restrict__ pH,
    const float* __restrict__ ub, const float* __restrict__ geom,
    float* __restrict__ p2)
{
    const int n = blockIdx.x * 256 + threadIdx.x;   // 0..BN-1
    float hxx = 0.0f, hxy = 0.0f, hyy = 0.0f, bx = 0.0f, by = 0.0f;
    #pragma unroll
    for (int k = 0; k < NCHUNK; ++k) {
        const float* o = pH + ((size_t)k * BN + n) * 5;
        hxx += o[0]; hxy += o[1]; hyy += o[2]; bx += o[3]; by += o[4];
    }

    const float2 u  = ((const float2*)ub)[n];
    const float2 xs = ((const float2*)geom)[n];

    const float A  = hxx + EPSq;
    const float Bv = hxy;
    const float D  = hyy + EPSq;

    const float det = A * D - Bv * Bv;
    const float inv = 1.0f / det;
    const float hbx = ( D * bx - Bv * by) * inv;
    const float hby = (-Bv * bx + A * by) * inv;
    const float dx = u.x - (xs.x - hbx);
    const float dy = u.y - (xs.y - hby);
    const float quad = A * dx * dx + 2.0f * Bv * dx * dy + D * dy * dy;

    const float detc = fmaxf(det, 1e-16f);
    p2[n]      = 0.5f * quad;
    p2[BN + n] = logf(detc);
}

// ---------------------------------------------------------------------------
// Single-block final reduction -> (e, e1, e2)
// ---------------------------------------------------------------------------
__global__ __launch_bounds__(1024) void gn_reduce_kernel(
    const float* __restrict__ p2, float* __restrict__ out)
{
    float s1 = 0.0f, s2 = 0.0f;
    for (int i = threadIdx.x; i < BN; i += 1024) {
        s1 += p2[i];
        s2 += p2[BN + i];
    }
    #pragma unroll
    for (int off = 32; off > 0; off >>= 1) {
        s1 += __shfl_down(s1, off);
        s2 += __shfl_down(s2, off);
    }
    __shared__ float l1[16], l2[16];
    const int w = threadIdx.x >> 6;
    if ((threadIdx.x & 63) == 0) { l1[w] = s1; l2[w] = s2; }
    __syncthreads();
    if (threadIdx.x == 0) {
        float e1 = 0.0f, sl = 0.0f;
        #pragma unroll
        for (int i = 0; i < 16; ++i) { e1 += l1[i]; sl += l2[i]; }
        const float e2 = (float)BN * LOG_2PI - 0.5f * sl;
        out[0] = e1 + (2.0f / 7.0f) * e2;  // e
        out[1] = e1;
        out[2] = e2;
    }
}

extern "C" void kernel_launch(void* const* d_in, const int* in_sizes, int n_in,
                              void* d_out, int out_size, void* d_ws, size_t ws_size,
                              hipStream_t stream) {
    const float* fb    = (const float*)d_in[0];
    const float* f_t   = (const float*)d_in[1];
    const float* ub    = (const float*)d_in[2];
    const float* noise = (const float*)d_in[3];
    float* out = (float*)d_out;
    int*   wsi = (int*)d_ws;
    float* wsf = (float*)d_ws;

    int*   bc   = wsi;                // 256 ints
    int*   bs   = wsi + BS_OFF;       // 256 * 1024 ints
    float* geom = wsf + GEOM_OFF;     // [BN] float2
    float* pH   = wsf + PH_OFF;       // [16][8192][5]
    float* p2   = wsf + P2_OFF;       // [2][8192]

    zero_bins<<<1, NBINS, 0, stream>>>(bc);
    binprep<<<BN / 256, 256, 0, stream>>>(ub, noise, bc, bs, geom);
    gn_binned<<<NBINS * NCHUNK, 512, 0, stream>>>(fb, f_t, bc, bs, geom, pH);
    gn_finalA<<<BN / 256, 256, 0, stream>>>(pH, ub, geom, p2);
    gn_reduce_kernel<<<1, 1024, 0, stream>>>(p2, out);
}